// Round 8
// baseline (417.162 us; speedup 1.0000x reference)
//
#include <hip/hip_runtime.h>
#include <hip/hip_bf16.h>

// SpatialAttention: B=4, H=W=64, C=D=256. N=4096 tokens/batch.
// fp32->bf16, QKV proj (MFMA, W staged in LDS), split-K flash attn with
// SWAPPED QK. v8: IN-REGISTER P (T12). Each wave owns 16 rows end-to-end:
// QK (swapped) -> exp -> cvt_pk -> ONE shfl_xor(16) pair assembles the
// PV A-fragment in-register (token-block permutation B0,B2,B1,B3 folded
// into V's load offset) -> PV over ALL 256 d-cols for its 16 rows.
// No P LDS, no P barrier, no cross-wave data dependency: ONE
// __syncthreads per 32 tokens (K-DMA handoff only). V read from global
// V^T (L1-resident 16 KB tile). Keeps v6's cohort swizzle (FETCH 70->19MB)
// and v1 proj/oproj. Evidence: v1-v7 falsified volume/drain/locality/
// barrier-count theories; remaining pin = cross-wave P lockstep.
// No-max softmax => unnormalized partials; combine folded into out-proj.

typedef __attribute__((ext_vector_type(8))) short short8;
typedef __attribute__((ext_vector_type(4))) short short4v;
typedef __attribute__((ext_vector_type(4))) float floatx4;

#define NB 4
#define NT 4096
#define CD 256
#define MTOT (NB * NT)   // 16384

__device__ __forceinline__ short bf16s(float f) {
    union { float f; unsigned u; } a; a.f = f;
    unsigned u = a.u;
    return (short)((u + 0x7fffu + ((u >> 16) & 1u)) >> 16);   // RNE
}

__device__ __forceinline__ float bf2f(short s) {
    union { unsigned u; float f; } a;
    a.u = ((unsigned)(unsigned short)s) << 16;
    return a.f;
}

__device__ __forceinline__ short8 ld8(const short* p) {
    return *(const short8*)p;
}

__device__ __forceinline__ floatx4 mfma16(short8 a, short8 b, floatx4 c) {
    return __builtin_amdgcn_mfma_f32_16x16x32_bf16(a, b, c, 0, 0, 0);
}

// async global->LDS DMA, 16 B/lane; LDS dest = wave-uniform base + lane*16
__device__ __forceinline__ void dma16(const void* g, void* l) {
    __builtin_amdgcn_global_load_lds(
        (const __attribute__((address_space(1))) void*)g,
        (__attribute__((address_space(3))) void*)l, 16, 0, 0);
}

// ---- convert features fp32 -> bf16 [16384 x 256] row-major ----
__global__ __launch_bounds__(256) void k_convx(const float* __restrict__ x,
                                               short* __restrict__ xb) {
    int i = (blockIdx.x * 256 + threadIdx.x) * 4;
    float4 v = *(const float4*)(x + i);
    short4v o;
    o.x = bf16s(v.x); o.y = bf16s(v.y); o.z = bf16s(v.z); o.w = bf16s(v.w);
    *(short4v*)(xb + i) = o;
}

// ---- convert + transpose weights: Wt[z][n][c] = W_z[c][n], bf16 ----
__global__ __launch_bounds__(256) void k_convw(const float* __restrict__ w0,
                                               const float* __restrict__ w1,
                                               const float* __restrict__ w2,
                                               const float* __restrict__ w3,
                                               short* __restrict__ wt) {
    int z = blockIdx.y;
    const float* w = (z == 0) ? w0 : (z == 1) ? w1 : (z == 2) ? w2 : w3;
    int c = blockIdx.x;
    int n = threadIdx.x;
    wt[z * 65536 + n * 256 + c] = bf16s(w[c * 256 + n]);
}

// ---- fused QKV projection: block = 256 thr = 4 waves, 128m x 64n tile ----
__global__ __launch_bounds__(256) void k_proj3(const short* __restrict__ A,
                                               const short* __restrict__ Wt,
                                               const float* __restrict__ bq,
                                               const float* __restrict__ bk,
                                               const float* __restrict__ bv,
                                               short* __restrict__ Qb,
                                               short* __restrict__ Kb,
                                               short* __restrict__ Vt) {
    __shared__ __align__(16) short Ws[16384];
    int z = blockIdx.z;
    const short* W = Wt + z * 65536;
    const float* bias = (z == 0) ? bq : (z == 1) ? bk : bv;
    float scale = (z == 0) ? 0.0625f : 1.0f;   // fold 1/sqrt(256) into Q
    int m0 = blockIdx.x * 128;
    int n0 = blockIdx.y * 64;
    int tid = threadIdx.x;
    int w = tid >> 6, l = tid & 63, r = l & 15, q = l >> 4;

#pragma unroll
    for (int cg = 0; cg < 8; ++cg)
        dma16(W + (size_t)(n0 + w * 16 + r) * CD + (cg * 4 + q) * 8,
              &Ws[w * 4096 + cg * 512]);
    __syncthreads();

    const short* a0 = A + (size_t)(m0 + w * 32 + r) * CD;
    const short* a1 = a0 + 16 * CD;
    floatx4 acc[2][4];
#pragma unroll
    for (int rt = 0; rt < 2; ++rt)
#pragma unroll
        for (int j = 0; j < 4; ++j) acc[rt][j] = (floatx4){0.f, 0.f, 0.f, 0.f};
#pragma unroll
    for (int c = 0; c < 8; ++c) {
        short8 af0 = ld8(a0 + c * 32 + q * 8);
        short8 af1 = ld8(a1 + c * 32 + q * 8);
#pragma unroll
        for (int j = 0; j < 4; ++j) {
            short8 wf = ld8(&Ws[j * 4096 + c * 512 + l * 8]);
            acc[0][j] = mfma16(af0, wf, acc[0][j]);
            acc[1][j] = mfma16(af1, wf, acc[1][j]);
        }
    }
#pragma unroll
    for (int rt = 0; rt < 2; ++rt)
#pragma unroll
        for (int j = 0; j < 4; ++j) {
            int col = n0 + j * 16 + r;
            float bvv = bias[col];
#pragma unroll
            for (int i = 0; i < 4; ++i) {
                int row = m0 + w * 32 + rt * 16 + q * 4 + i;
                short s = bf16s((acc[rt][j][i] + bvv) * scale);
                if (z == 0) Qb[(size_t)row * CD + col] = s;
                else if (z == 1) Kb[(size_t)row * CD + col] = s;
                else {
                    int bb = row >> 12, lm = row & (NT - 1);
                    Vt[((size_t)bb * CD + col) * NT + lm] = s;
                }
            }
        }
}

// ---- split-K flash attention v8: BM=64, 4 waves, in-register P ----
// 1-D XCD-swizzled grid (cohort-major). Wave w owns rows m0+w*16..+16:
// QK-swap vs 32 tokens -> exp -> cvt_pk + shfl_xor(16) -> A-fragment
// in-register -> PV over all 256 cols (16 MFMAs, V from global V^T with
// token-permutation pb folded into the load offset). One __syncthreads
// per iteration (K dbuf handoff). Partials: O bf16 + l fp32.
__global__ __launch_bounds__(256, 3) void k_attn(const short* __restrict__ Qb,
                                                 const short* __restrict__ Kb,
                                                 const short* __restrict__ Vt,
                                                 short* __restrict__ Op0,
                                                 short* __restrict__ Op1,
                                                 short* __restrict__ Op2,
                                                 float* __restrict__ Lp,
                                                 int nks) {
    __shared__ __align__(16) short Ks[2][8192];   // 2 x 16 KB (no P buffer)

    const int tid = threadIdx.x;
    const int w = tid >> 6;
    const int l = tid & 63;
    const int r = l & 15, q = l >> 4;
    const int pb = ((q & 1) << 1) | (q >> 1);   // token-block perm B0,B2,B1,B3
    // 1-D swizzled decode: nbk = 64*NB*nks, nbk % 8 == 0 -> bijective
    const int nbk = gridDim.x;
    const int blk = blockIdx.x;
    const int wk = (blk & 7) * (nbk >> 3) + (blk >> 3);
    const int bx = wk & 63;          // x fastest within cohort
    const int co = wk >> 6;          // cohort = b*nks + ks
    const int b = co / nks;
    const int ks = co - b * nks;
    const int m0 = bx * 64;
    // token range: 128 units of 32 tokens split across nks
    const int qq = 128 / nks, rem = 128 % nks;
    const int u0 = ks * qq + (ks < rem ? ks : rem);
    const int cnt = qq + (ks < rem ? 1 : 0);
    const int t0 = u0 * 32;
    const int tt_d = w & 1;               // DMA token-subtile
    const int cb_d = (w >> 1) * 4;        // DMA chunk-group base
    const short* Qp = Qb + (size_t)b * NT * CD;
    const short* Kp = Kb + (size_t)b * NT * CD;
    const short* Vp = Vt + (size_t)b * CD * NT;   // [256][4096]
    short* Op = (ks == 0) ? Op0 : (ks == 1) ? Op1 : Op2;

    // Q fragments (B-operand): rows m0 + w*16 + r, Q pre-scaled by 1/16
    short8 qf[8];
#pragma unroll
    for (int c = 0; c < 8; ++c)
        qf[c] = ld8(Qp + (size_t)(m0 + w * 16 + r) * CD + c * 32 + q * 8);

    // accumulator: rows m0+w*16.. (16) x cols dt*16+r (dt=0..15 -> 256)
    floatx4 o[16];
#pragma unroll
    for (int dt = 0; dt < 16; ++dt) o[dt] = (floatx4){0.f, 0.f, 0.f, 0.f};
    float ls = 0.f;

    // prologue: DMA K tile 0 into Ks[0]
#pragma unroll
    for (int j = 0; j < 4; ++j)
        dma16(Kp + (size_t)(t0 + tt_d * 16 + r) * CD + ((cb_d + j) * 4 + q) * 8,
              &Ks[0][tt_d * 4096 + (cb_d + j) * 512]);

#pragma unroll 1
    for (int it = 0; it < cnt; ++it) {
        const int p = it & 1;
        const int n0 = t0 + it * 32;
        __syncthreads();   // drains vmcnt(0): Ks[p] DMA complete (only sync)

        // refill next K tile into the other buffer (drained at next barrier;
        // prior readers of Ks[1-p] all retired pre-barrier)
        if (it + 1 < cnt) {
#pragma unroll
            for (int j = 0; j < 4; ++j)
                dma16(Kp + (size_t)(n0 + 32 + tt_d * 16 + r) * CD + ((cb_d + j) * 4 + q) * 8,
                      &Ks[1 - p][tt_d * 4096 + (cb_d + j) * 512]);
        }

        // V fragment group 0 (cols u*16+r, permuted token base) — latency
        // hides under QK
        const short* vbase = Vp + n0 + pb * 8 + (size_t)r * NT;
        short8 vfp[4], vfn[4];
#pragma unroll
        for (int u = 0; u < 4; ++u)
            vfp[u] = ld8(vbase + (size_t)(u * 16) * NT);

        // QK swapped: S^T; lane (r,q) s{0,1}[i] = S[row m0+w*16+r][tok n0+tt*16+q*4+i]
        floatx4 s0 = {0.f, 0.f, 0.f, 0.f};
        floatx4 s1 = {0.f, 0.f, 0.f, 0.f};
#pragma unroll
        for (int c = 0; c < 8; ++c) {
            s0 = mfma16(ld8(&Ks[p][c * 512 + l * 8]), qf[c], s0);
            s1 = mfma16(ld8(&Ks[p][4096 + c * 512 + l * 8]), qf[c], s1);
        }

        // exp + lsum + pack: pk0* = tokens q*4..+4 (tt0), pk1* = 16+q*4..+4 (tt1)
        float a0 = __expf(s0[0]), a1 = __expf(s0[1]);
        float a2 = __expf(s0[2]), a3 = __expf(s0[3]);
        float b0 = __expf(s1[0]), b1 = __expf(s1[1]);
        float b2 = __expf(s1[2]), b3 = __expf(s1[3]);
        ls += (a0 + a1) + (a2 + a3) + (b0 + b1) + (b2 + b3);
        unsigned pk00, pk01, pk10, pk11;
        asm("v_cvt_pk_bf16_f32 %0, %1, %2" : "=v"(pk00) : "v"(a0), "v"(a1));
        asm("v_cvt_pk_bf16_f32 %0, %1, %2" : "=v"(pk01) : "v"(a2), "v"(a3));
        asm("v_cvt_pk_bf16_f32 %0, %1, %2" : "=v"(pk10) : "v"(b0), "v"(b1));
        asm("v_cvt_pk_bf16_f32 %0, %1, %2" : "=v"(pk11) : "v"(b2), "v"(b3));

        // in-register A-fragment assembly: pair (q, q^1) exchange.
        // even q sends its tt1 pair, odd q sends its tt0 pair.
        unsigned sw0 = (q & 1) ? pk00 : pk10;
        unsigned sw1 = (q & 1) ? pk01 : pk11;
        unsigned rw0 = __shfl_xor(sw0, 16);
        unsigned rw1 = __shfl_xor(sw1, 16);
        union { unsigned u[4]; short8 v; } pu;
        pu.u[0] = (q & 1) ? rw0 : pk00;
        pu.u[1] = (q & 1) ? rw1 : pk01;
        pu.u[2] = (q & 1) ? pk10 : rw0;
        pu.u[3] = (q & 1) ? pk11 : rw1;
        short8 pfv = pu.v;   // A[row r][k=q*8..+8] under perm pb

        // PV: o[dt] += P x V, dt-groups of 4 with one-group load lookahead
#pragma unroll
        for (int g = 0; g < 4; ++g) {
            if (g < 3) {
#pragma unroll
                for (int u = 0; u < 4; ++u)
                    vfn[u] = ld8(vbase + (size_t)((g + 1) * 4 + u) * 16 * NT);
            }
#pragma unroll
            for (int u = 0; u < 4; ++u)
                o[g * 4 + u] = mfma16(pfv, vfp[u], o[g * 4 + u]);
#pragma unroll
            for (int u = 0; u < 4; ++u) vfp[u] = vfn[u];
        }
    }

    // partial lsum: lane (r,q) holds row m0+w*16+r partial; reduce across q
    ls += __shfl_xor(ls, 16);
    ls += __shfl_xor(ls, 32);
    if (l < 16)
        Lp[(size_t)ks * MTOT + b * NT + m0 + w * 16 + l] = ls;

    // unnormalized partial O store: rows m0+w*16+q*4+i, cols dt*16+r
#pragma unroll
    for (int dt = 0; dt < 16; ++dt)
#pragma unroll
        for (int i = 0; i < 4; ++i) {
            int row = m0 + w * 16 + q * 4 + i;
            Op[((size_t)b * NT + row) * CD + dt * 16 + r] = bf16s(o[dt][i]);
        }
}

// ---- output projection + split-K combine: A = (sum Opk)/(sum lk), fp32 out
__global__ __launch_bounds__(256) void k_oproj(const short* __restrict__ Op0,
                                               const short* __restrict__ Op1,
                                               const short* __restrict__ Op2,
                                               const float* __restrict__ Lp,
                                               const short* __restrict__ Wot,
                                               const float* __restrict__ bo,
                                               float* __restrict__ out, int nks) {
    __shared__ __align__(16) short Ws[16384];
    int m0 = blockIdx.x * 128;
    int n0 = blockIdx.y * 64;
    int tid = threadIdx.x;
    int w = tid >> 6, l = tid & 63, r = l & 15, q = l >> 4;

#pragma unroll
    for (int cg = 0; cg < 8; ++cg)
        dma16(Wot + (size_t)(n0 + w * 16 + r) * CD + (cg * 4 + q) * 8,
              &Ws[w * 4096 + cg * 512]);
    __syncthreads();

    int row0 = m0 + w * 32 + r;
    float lt0 = Lp[row0] + Lp[MTOT + row0];
    float lt1 = Lp[row0 + 16] + Lp[MTOT + row0 + 16];
    if (nks == 3) { lt0 += Lp[2 * (size_t)MTOT + row0]; lt1 += Lp[2 * (size_t)MTOT + row0 + 16]; }
    float inv0 = 1.0f / lt0, inv1 = 1.0f / lt1;
    const short* p0 = Op0 + (size_t)row0 * CD;
    const short* p1 = Op1 + (size_t)row0 * CD;
    const short* p2 = Op2 + (size_t)row0 * CD;
    floatx4 acc[2][4];
#pragma unroll
    for (int rt = 0; rt < 2; ++rt)
#pragma unroll
        for (int j = 0; j < 4; ++j) acc[rt][j] = (floatx4){0.f, 0.f, 0.f, 0.f};
#pragma unroll
    for (int c = 0; c < 8; ++c) {
        int off0 = c * 32 + q * 8, off1 = 16 * CD + c * 32 + q * 8;
        short8 x0 = ld8(p0 + off0), y0 = ld8(p1 + off0);
        short8 x1 = ld8(p0 + off1), y1 = ld8(p1 + off1);
        short8 af0, af1;
        if (nks == 3) {
            short8 z0 = ld8(p2 + off0), z1 = ld8(p2 + off1);
#pragma unroll
            for (int jj = 0; jj < 8; ++jj) {
                af0[jj] = bf16s((bf2f(x0[jj]) + bf2f(y0[jj]) + bf2f(z0[jj])) * inv0);
                af1[jj] = bf16s((bf2f(x1[jj]) + bf2f(y1[jj]) + bf2f(z1[jj])) * inv1);
            }
        } else {
#pragma unroll
            for (int jj = 0; jj < 8; ++jj) {
                af0[jj] = bf16s((bf2f(x0[jj]) + bf2f(y0[jj])) * inv0);
                af1[jj] = bf16s((bf2f(x1[jj]) + bf2f(y1[jj])) * inv1);
            }
        }
#pragma unroll
        for (int j = 0; j < 4; ++j) {
            short8 wf = ld8(&Ws[j * 4096 + c * 512 + l * 8]);
            acc[0][j] = mfma16(af0, wf, acc[0][j]);
            acc[1][j] = mfma16(af1, wf, acc[1][j]);
        }
    }
#pragma unroll
    for (int rt = 0; rt < 2; ++rt)
#pragma unroll
        for (int j = 0; j < 4; ++j) {
            int col = n0 + j * 16 + r;
            float bvv = bo[col];
#pragma unroll
            for (int i = 0; i < 4; ++i)
                out[(size_t)(m0 + w * 32 + rt * 16 + q * 4 + i) * CD + col] =
                    acc[rt][j][i] + bvv;
        }
}

extern "C" void kernel_launch(void* const* d_in, const int* in_sizes, int n_in,
                              void* d_out, int out_size, void* d_ws, size_t ws_size,
                              hipStream_t stream) {
    const float* x  = (const float*)d_in[0];
    const float* Wq = (const float*)d_in[1];
    const float* bq = (const float*)d_in[2];
    const float* Wk = (const float*)d_in[3];
    const float* bk = (const float*)d_in[4];
    const float* Wv = (const float*)d_in[5];
    const float* bv = (const float*)d_in[6];
    const float* Wo = (const float*)d_in[7];
    const float* bo = (const float*)d_in[8];
    float* out = (float*)d_out;

    char* ws = (char*)d_ws;
    const size_t MB = 1024u * 1024u;
    short* xb  = (short*)(ws);             // 8 MB: x bf16; DEAD after proj3 ->
    short* Op0 = (short*)(ws);             //        reused as partial-O (ks=0)
    short* Qb  = (short*)(ws + 8 * MB);    // 8 MB: Q*scale bf16
    short* Kb  = (short*)(ws + 16 * MB);   // 8 MB: K bf16
    short* Vt  = (short*)(ws + 24 * MB);   // 8 MB: V^T bf16 [4][256][4096]
    short* Op1 = (short*)(ws + 32 * MB);   // 8 MB: partial-O (ks=1)
    short* Wt  = (short*)(ws + 40 * MB);   // 512 KB: transposed weights bf16
    float* Lp  = (float*)(ws + 40 * MB + 512 * 1024);  // 192 KB: partial l [3][16384]
    short* Op2 = (short*)(ws + 41 * MB);   // 8 MB: partial-O (ks=2), if ws allows

    // 3-way split-K (768 blocks = 3/CU) when workspace permits, else 2-way.
    int nks = (ws_size >= 49 * MB + 512 * 1024) ? 3 : 2;
    if (nks == 2) Op2 = Op1;   // unused, keep pointer valid

    k_convx<<<dim3(MTOT * CD / (256 * 4)), 256, 0, stream>>>(x, xb);
    k_convw<<<dim3(256, 4), 256, 0, stream>>>(Wq, Wk, Wv, Wo, Wt);
    k_proj3<<<dim3(MTOT / 128, CD / 64, 3), 256, 0, stream>>>(xb, Wt, bq, bk, bv, Qb, Kb, Vt);
    k_attn<<<dim3(64 * NB * nks), 256, 0, stream>>>(Qb, Kb, Vt, Op0, Op1, Op2, Lp, nks);
    k_oproj<<<dim3(MTOT / 128, CD / 64), 256, 0, stream>>>(Op0, Op1, Op2, Lp, Wt + 196608, bo, out, nks);
}

// Round 9
// 261.692 us; speedup vs baseline: 1.5941x; 1.5941x over previous
//
#include <hip/hip_runtime.h>
#include <hip/hip_bf16.h>

// SpatialAttention: B=4, H=W=64, C=D=256. N=4096 tokens/batch.
// v9 = consolidation of best-measured config after 8 structural probes
// (v1..v8) all failed to beat the 146 us attn plateau:
//   - attn: v1 inner loop (BM=64, BN=32, 4 waves, global_load_lds K dbuf,
//     2 barriers/iter, nks=3, launch_bounds(256,3) -> 84 VGPR no spill)
//     + XCD cohort swizzle (FETCH 70->19 MB, v5/v6-proven) + cvt_pk P
//     packing (v4-proven) + NEW: s_setprio(1) around MFMA clusters (T5,
//     attn-positive in within-probe A/B; 3 independent blocks/CU give the
//     phase diversity the mechanism needs).
//   - proj3/oproj: v1 2-D grid forms (v6's 1-D swizzles cost ~11 us).
//   - prep: convx+convw merged into one kernel (one fewer launch).
// No-max softmax => unnormalized partials; combine folded into out-proj.

typedef __attribute__((ext_vector_type(8))) short short8;
typedef __attribute__((ext_vector_type(4))) short short4v;
typedef __attribute__((ext_vector_type(4))) float floatx4;

#define NB 4
#define NT 4096
#define CD 256
#define MTOT (NB * NT)   // 16384

__device__ __forceinline__ short bf16s(float f) {
    union { float f; unsigned u; } a; a.f = f;
    unsigned u = a.u;
    return (short)((u + 0x7fffu + ((u >> 16) & 1u)) >> 16);   // RNE
}

__device__ __forceinline__ float bf2f(short s) {
    union { unsigned u; float f; } a;
    a.u = ((unsigned)(unsigned short)s) << 16;
    return a.f;
}

__device__ __forceinline__ short8 ld8(const short* p) {
    return *(const short8*)p;
}

__device__ __forceinline__ floatx4 mfma16(short8 a, short8 b, floatx4 c) {
    return __builtin_amdgcn_mfma_f32_16x16x32_bf16(a, b, c, 0, 0, 0);
}

// async global->LDS DMA, 16 B/lane; LDS dest = wave-uniform base + lane*16
__device__ __forceinline__ void dma16(const void* g, void* l) {
    __builtin_amdgcn_global_load_lds(
        (const __attribute__((address_space(1))) void*)g,
        (__attribute__((address_space(3))) void*)l, 16, 0, 0);
}

// ---- merged prep: blocks [0,4096) convert x fp32->bf16 [16384x256];
// blocks [4096,5120) convert+transpose weights Wt[z][n][c] = W_z[c][n] ----
__global__ __launch_bounds__(256) void k_prep(const float* __restrict__ x,
                                              short* __restrict__ xb,
                                              const float* __restrict__ w0,
                                              const float* __restrict__ w1,
                                              const float* __restrict__ w2,
                                              const float* __restrict__ w3,
                                              short* __restrict__ wt) {
    int blk = blockIdx.x;
    if (blk < 4096) {
        int i = (blk * 256 + threadIdx.x) * 4;
        float4 v = *(const float4*)(x + i);
        short4v o;
        o.x = bf16s(v.x); o.y = bf16s(v.y); o.z = bf16s(v.z); o.w = bf16s(v.w);
        *(short4v*)(xb + i) = o;
    } else {
        int t = blk - 4096;              // 1024 blocks: z = t>>8, c = t&255
        int z = t >> 8, c = t & 255;
        const float* w = (z == 0) ? w0 : (z == 1) ? w1 : (z == 2) ? w2 : w3;
        int n = threadIdx.x;
        wt[z * 65536 + n * 256 + c] = bf16s(w[c * 256 + n]);
    }
}

// ---- fused QKV projection: block = 256 thr = 4 waves, 128m x 64n tile ----
__global__ __launch_bounds__(256) void k_proj3(const short* __restrict__ A,
                                               const short* __restrict__ Wt,
                                               const float* __restrict__ bq,
                                               const float* __restrict__ bk,
                                               const float* __restrict__ bv,
                                               short* __restrict__ Qb,
                                               short* __restrict__ Kb,
                                               short* __restrict__ Vt) {
    __shared__ __align__(16) short Ws[16384];
    int z = blockIdx.z;
    const short* W = Wt + z * 65536;
    const float* bias = (z == 0) ? bq : (z == 1) ? bk : bv;
    float scale = (z == 0) ? 0.0625f : 1.0f;   // fold 1/sqrt(256) into Q
    int m0 = blockIdx.x * 128;
    int n0 = blockIdx.y * 64;
    int tid = threadIdx.x;
    int w = tid >> 6, l = tid & 63, r = l & 15, q = l >> 4;

#pragma unroll
    for (int cg = 0; cg < 8; ++cg)
        dma16(W + (size_t)(n0 + w * 16 + r) * CD + (cg * 4 + q) * 8,
              &Ws[w * 4096 + cg * 512]);
    __syncthreads();

    const short* a0 = A + (size_t)(m0 + w * 32 + r) * CD;
    const short* a1 = a0 + 16 * CD;
    floatx4 acc[2][4];
#pragma unroll
    for (int rt = 0; rt < 2; ++rt)
#pragma unroll
        for (int j = 0; j < 4; ++j) acc[rt][j] = (floatx4){0.f, 0.f, 0.f, 0.f};
#pragma unroll
    for (int c = 0; c < 8; ++c) {
        short8 af0 = ld8(a0 + c * 32 + q * 8);
        short8 af1 = ld8(a1 + c * 32 + q * 8);
#pragma unroll
        for (int j = 0; j < 4; ++j) {
            short8 wf = ld8(&Ws[j * 4096 + c * 512 + l * 8]);
            acc[0][j] = mfma16(af0, wf, acc[0][j]);
            acc[1][j] = mfma16(af1, wf, acc[1][j]);
        }
    }
#pragma unroll
    for (int rt = 0; rt < 2; ++rt)
#pragma unroll
        for (int j = 0; j < 4; ++j) {
            int col = n0 + j * 16 + r;
            float bvv = bias[col];
#pragma unroll
            for (int i = 0; i < 4; ++i) {
                int row = m0 + w * 32 + rt * 16 + q * 4 + i;
                short s = bf16s((acc[rt][j][i] + bvv) * scale);
                if (z == 0) Qb[(size_t)row * CD + col] = s;
                else if (z == 1) Kb[(size_t)row * CD + col] = s;
                else {
                    int bb = row >> 12, lm = row & (NT - 1);
                    Vt[((size_t)bb * CD + col) * NT + lm] = s;
                }
            }
        }
}

// ---- split-K flash attention v9: v1 loop + cohort swizzle + setprio ----
// Works ordered cohort-major: work = (b*nks+ks)*64 + x, so each XCD owns
// whole cohorts; a cohort's 64 blocks stream the SAME K/V slab in the
// same iteration order -> L2-resident KV (FETCH 70->19 MB measured).
__global__ __launch_bounds__(256, 3) void k_attn(const short* __restrict__ Qb,
                                                 const short* __restrict__ Kb,
                                                 const short* __restrict__ Vt,
                                                 short* __restrict__ Op0,
                                                 short* __restrict__ Op1,
                                                 short* __restrict__ Op2,
                                                 float* __restrict__ Lp,
                                                 int nks) {
    __shared__ __align__(16) short Ks[2][8192];   // 2 x 16 KB
    __shared__ __align__(16) short P[64][36];     // [row][tok], pad 4

    const int tid = threadIdx.x;
    const int w = tid >> 6;
    const int l = tid & 63;
    const int r = l & 15, q = l >> 4;
    // 1-D swizzled decode: nbk = 64*NB*nks, nbk % 8 == 0 -> bijective
    const int nbk = gridDim.x;
    const int blk = blockIdx.x;
    const int wk = (blk & 7) * (nbk >> 3) + (blk >> 3);
    const int bx = wk & 63;          // x fastest within cohort
    const int co = wk >> 6;          // cohort = b*nks + ks
    const int b = co / nks;
    const int ks = co - b * nks;
    const int m0 = bx * 64;
    // token range: 128 units of 32 tokens split across nks
    const int qq = 128 / nks, rem = 128 % nks;
    const int u0 = ks * qq + (ks < rem ? ks : rem);
    const int cnt = qq + (ks < rem ? 1 : 0);
    const int t0 = u0 * 32;
    const int tt_d = w & 1;               // DMA token-subtile
    const int cb_d = (w >> 1) * 4;        // DMA chunk-group base
    const short* Qp = Qb + (size_t)b * NT * CD;
    const short* Kp = Kb + (size_t)b * NT * CD;
    const short* Vp = Vt + (size_t)b * CD * NT;   // [256][4096]
    short* Op = (ks == 0) ? Op0 : (ks == 1) ? Op1 : Op2;

    // Q fragments (B-operand): rows m0 + w*16 + r, Q pre-scaled by 1/16
    short8 qf[8];
#pragma unroll
    for (int c = 0; c < 8; ++c)
        qf[c] = ld8(Qp + (size_t)(m0 + w * 16 + r) * CD + c * 32 + q * 8);

    floatx4 o[4][4];
#pragma unroll
    for (int rt = 0; rt < 4; ++rt)
#pragma unroll
        for (int dt = 0; dt < 4; ++dt) o[rt][dt] = (floatx4){0.f, 0.f, 0.f, 0.f};
    float ls = 0.f;

    // prologue: DMA K tile 0 into Ks[0]
#pragma unroll
    for (int j = 0; j < 4; ++j)
        dma16(Kp + (size_t)(t0 + tt_d * 16 + r) * CD + ((cb_d + j) * 4 + q) * 8,
              &Ks[0][tt_d * 4096 + (cb_d + j) * 512]);

#pragma unroll 1
    for (int it = 0; it < cnt; ++it) {
        const int p = it & 1;
        const int n0 = t0 + it * 32;
        __syncthreads();   // drains vmcnt(0): Ks[p] DMA complete, P consumed

        // V fragments for THIS iter (before next DMA so their wait leaves DMA in flight)
        short8 vf[4];
#pragma unroll
        for (int dt = 0; dt < 4; ++dt)
            vf[dt] = ld8(Vp + (size_t)(w * 64 + dt * 16 + r) * NT + n0 + q * 8);

        if (it + 1 < cnt) {
#pragma unroll
            for (int j = 0; j < 4; ++j)
                dma16(Kp + (size_t)(n0 + 32 + tt_d * 16 + r) * CD + ((cb_d + j) * 4 + q) * 8,
                      &Ks[1 - p][tt_d * 4096 + (cb_d + j) * 512]);
        }

        // QK swapped: S^T tiles; lane (r,q) reg i = S[row m0+w*16+r][tok n0+tt*16+q*4+i]
        floatx4 s0 = {0.f, 0.f, 0.f, 0.f};
        floatx4 s1 = {0.f, 0.f, 0.f, 0.f};
        __builtin_amdgcn_s_setprio(1);
#pragma unroll
        for (int c = 0; c < 8; ++c) {
            s0 = mfma16(ld8(&Ks[p][c * 512 + l * 8]), qf[c], s0);
            s1 = mfma16(ld8(&Ks[p][4096 + c * 512 + l * 8]), qf[c], s1);
        }
        __builtin_amdgcn_s_setprio(0);

        // exp + scalar lsum + packed cvt_pk b64 P writes (4 bf16 each)
#pragma unroll
        for (int tt = 0; tt < 2; ++tt) {
            floatx4 sv = tt ? s1 : s0;
            float e0 = __expf(sv[0]), e1 = __expf(sv[1]);
            float e2 = __expf(sv[2]), e3 = __expf(sv[3]);
            ls += (e0 + e1) + (e2 + e3);
            unsigned pk01, pk23;
            asm("v_cvt_pk_bf16_f32 %0, %1, %2" : "=v"(pk01) : "v"(e0), "v"(e1));
            asm("v_cvt_pk_bf16_f32 %0, %1, %2" : "=v"(pk23) : "v"(e2), "v"(e3));
            uint2 pk; pk.x = pk01; pk.y = pk23;
            *(uint2*)&P[w * 16 + r][tt * 16 + q * 4] = pk;
        }
        // P visible block-wide; NOT __syncthreads (would drain the K DMA)
        asm volatile("s_waitcnt lgkmcnt(0)\n\ts_barrier" ::: "memory");

        // PV: o[rt][dt] += P[rt rows][tok] x V[d-slice][tok]
        __builtin_amdgcn_s_setprio(1);
#pragma unroll
        for (int rt = 0; rt < 4; ++rt) {
            short8 pf = ld8(&P[rt * 16 + r][q * 8]);
#pragma unroll
            for (int dt = 0; dt < 4; ++dt)
                o[rt][dt] = mfma16(pf, vf[dt], o[rt][dt]);
        }
        __builtin_amdgcn_s_setprio(0);
    }

    // partial lsum: lane (r,q) holds row m0+w*16+r partial; reduce across q
    ls += __shfl_xor(ls, 16);
    ls += __shfl_xor(ls, 32);
    if (l < 16)
        Lp[(size_t)ks * MTOT + b * NT + m0 + w * 16 + l] = ls;

    // unnormalized partial O store (cols w*64..+64, all 64 rows)
#pragma unroll
    for (int rt = 0; rt < 4; ++rt)
#pragma unroll
        for (int i = 0; i < 4; ++i) {
            int row = m0 + rt * 16 + q * 4 + i;
#pragma unroll
            for (int dt = 0; dt < 4; ++dt)
                Op[((size_t)b * NT + row) * CD + w * 64 + dt * 16 + r] =
                    bf16s(o[rt][dt][i]);
        }
}

// ---- output projection + split-K combine: A = (sum Opk)/(sum lk), fp32 out
__global__ __launch_bounds__(256) void k_oproj(const short* __restrict__ Op0,
                                               const short* __restrict__ Op1,
                                               const short* __restrict__ Op2,
                                               const float* __restrict__ Lp,
                                               const short* __restrict__ Wot,
                                               const float* __restrict__ bo,
                                               float* __restrict__ out, int nks) {
    __shared__ __align__(16) short Ws[16384];
    int m0 = blockIdx.x * 128;
    int n0 = blockIdx.y * 64;
    int tid = threadIdx.x;
    int w = tid >> 6, l = tid & 63, r = l & 15, q = l >> 4;

#pragma unroll
    for (int cg = 0; cg < 8; ++cg)
        dma16(Wot + (size_t)(n0 + w * 16 + r) * CD + (cg * 4 + q) * 8,
              &Ws[w * 4096 + cg * 512]);
    __syncthreads();

    int row0 = m0 + w * 32 + r;
    float lt0 = Lp[row0] + Lp[MTOT + row0];
    float lt1 = Lp[row0 + 16] + Lp[MTOT + row0 + 16];
    if (nks == 3) { lt0 += Lp[2 * (size_t)MTOT + row0]; lt1 += Lp[2 * (size_t)MTOT + row0 + 16]; }
    float inv0 = 1.0f / lt0, inv1 = 1.0f / lt1;
    const short* p0 = Op0 + (size_t)row0 * CD;
    const short* p1 = Op1 + (size_t)row0 * CD;
    const short* p2 = Op2 + (size_t)row0 * CD;
    floatx4 acc[2][4];
#pragma unroll
    for (int rt = 0; rt < 2; ++rt)
#pragma unroll
        for (int j = 0; j < 4; ++j) acc[rt][j] = (floatx4){0.f, 0.f, 0.f, 0.f};
#pragma unroll
    for (int c = 0; c < 8; ++c) {
        int off0 = c * 32 + q * 8, off1 = 16 * CD + c * 32 + q * 8;
        short8 x0 = ld8(p0 + off0), y0 = ld8(p1 + off0);
        short8 x1 = ld8(p0 + off1), y1 = ld8(p1 + off1);
        short8 af0, af1;
        if (nks == 3) {
            short8 z0 = ld8(p2 + off0), z1 = ld8(p2 + off1);
#pragma unroll
            for (int jj = 0; jj < 8; ++jj) {
                af0[jj] = bf16s((bf2f(x0[jj]) + bf2f(y0[jj]) + bf2f(z0[jj])) * inv0);
                af1[jj] = bf16s((bf2f(x1[jj]) + bf2f(y1[jj]) + bf2f(z1[jj])) * inv1);
            }
        } else {
#pragma unroll
            for (int jj = 0; jj < 8; ++jj) {
                af0[jj] = bf16s((bf2f(x0[jj]) + bf2f(y0[jj])) * inv0);
                af1[jj] = bf16s((bf2f(x1[jj]) + bf2f(y1[jj])) * inv1);
            }
        }
#pragma unroll
        for (int j = 0; j < 4; ++j) {
            short8 wf = ld8(&Ws[j * 4096 + c * 512 + l * 8]);
            acc[0][j] = mfma16(af0, wf, acc[0][j]);
            acc[1][j] = mfma16(af1, wf, acc[1][j]);
        }
    }
#pragma unroll
    for (int rt = 0; rt < 2; ++rt)
#pragma unroll
        for (int j = 0; j < 4; ++j) {
            int col = n0 + j * 16 + r;
            float bvv = bo[col];
#pragma unroll
            for (int i = 0; i < 4; ++i)
                out[(size_t)(m0 + w * 32 + rt * 16 + q * 4 + i) * CD + col] =
                    acc[rt][j][i] + bvv;
        }
}

extern "C" void kernel_launch(void* const* d_in, const int* in_sizes, int n_in,
                              void* d_out, int out_size, void* d_ws, size_t ws_size,
                              hipStream_t stream) {
    const float* x  = (const float*)d_in[0];
    const float* Wq = (const float*)d_in[1];
    const float* bq = (const float*)d_in[2];
    const float* Wk = (const float*)d_in[3];
    const float* bk = (const float*)d_in[4];
    const float* Wv = (const float*)d_in[5];
    const float* bv = (const float*)d_in[6];
    const float* Wo = (const float*)d_in[7];
    const float* bo = (const float*)d_in[8];
    float* out = (float*)d_out;

    char* ws = (char*)d_ws;
    const size_t MB = 1024u * 1024u;
    short* xb  = (short*)(ws);             // 8 MB: x bf16; DEAD after proj3 ->
    short* Op0 = (short*)(ws);             //        reused as partial-O (ks=0)
    short* Qb  = (short*)(ws + 8 * MB);    // 8 MB: Q*scale bf16
    short* Kb  = (short*)(ws + 16 * MB);   // 8 MB: K bf16
    short* Vt  = (short*)(ws + 24 * MB);   // 8 MB: V^T bf16 [4][256][4096]
    short* Op1 = (short*)(ws + 32 * MB);   // 8 MB: partial-O (ks=1)
    short* Wt  = (short*)(ws + 40 * MB);   // 512 KB: transposed weights bf16
    float* Lp  = (float*)(ws + 40 * MB + 512 * 1024);  // 192 KB: partial l [3][16384]
    short* Op2 = (short*)(ws + 41 * MB);   // 8 MB: partial-O (ks=2), if ws allows

    // 3-way split-K (768 blocks = 3/CU) when workspace permits, else 2-way.
    int nks = (ws_size >= 49 * MB + 512 * 1024) ? 3 : 2;
    if (nks == 2) Op2 = Op1;   // unused, keep pointer valid

    k_prep<<<dim3(5120), 256, 0, stream>>>(x, xb, Wq, Wk, Wv, Wo, Wt);
    k_proj3<<<dim3(MTOT / 128, CD / 64, 3), 256, 0, stream>>>(xb, Wt, bq, bk, bv, Qb, Kb, Vt);
    k_attn<<<dim3(64 * NB * nks), 256, 0, stream>>>(Qb, Kb, Vt, Op0, Op1, Op2, Lp, nks);
    k_oproj<<<dim3(MTOT / 128, CD / 64), 256, 0, stream>>>(Op0, Op1, Op2, Lp, Wt + 196608, bo, out, nks);
}